// Round 13
// baseline (346.468 us; speedup 1.0000x reference)
//
#include <hip/hip_runtime.h>
#include <math.h>

#define BB 64
#define TT 128
#define HH 16
#define GG 64      // 4*H
#define IN0_ 65
#define VV 32000
#define NROWS (BB*TT)   // 8192
#define RSTRIDE 68      // insh row stride (floats), 16B-aligned
#define BOFF (TT*RSTRIDE)   // per-batch insh offset (floats)

typedef float f32x4 __attribute__((ext_vector_type(4)));

__device__ __forceinline__ float sigf(float x) {
    return 1.0f / (1.0f + __expf(-x));
}
__device__ __forceinline__ float tanhfast(float x) {
    return 1.0f - 2.0f / (__expf(2.0f * x) + 1.0f);
}
__device__ __forceinline__ float bcast(float v, int lane) {
    return __uint_as_float(__builtin_amdgcn_readlane(__float_as_uint(v), lane));
}

// ---------------- Kernel A: fused front, 2 batches per block -----------------------
// 32 blocks x 256 threads. Phase 1: 4 waves compute xp for 2 batches (in-place in
// LDS). Phase 2: wave 0 runs BOTH batches' recurrences interleaved in registers —
// two independent dependency chains per lane hide VALU/trans latency (1 wave/SIMD
// has no TLP; this supplies ILP instead). Weights shared across the two chains.
__global__ __launch_bounds__(256) void fused_front(const float* __restrict__ x,
                           const float* __restrict__ emb,
                           const float* __restrict__ Wih0, const float* __restrict__ bih0,
                           const float* __restrict__ bhh0,
                           const float* __restrict__ h0in, const float* __restrict__ c0in,
                           const float* __restrict__ Whh0,
                           const float* __restrict__ Wih1, const float* __restrict__ Whh1,
                           const float* __restrict__ bih1, const float* __restrict__ bhh1,
                           float* __restrict__ y1, float* __restrict__ outTail) {
    extern __shared__ float smem[];           // [2*BOFF] insh(A,B) + [GG*IN0_] wsh
    float* wsh = smem + 2 * BOFF;
    const int b0  = blockIdx.x * 2;           // batches b0, b0+1
    const int tid = threadIdx.x;
    const int wave = tid >> 6, g = tid & 63;
    const float* xg = x + (size_t)b0 * TT * 9;   // 256 rows of 9

    // stage Wih0 into wsh (coalesced float4)
    for (int i = tid; i < GG * IN0_ / 4; i += 256) {
        float4 wv = *reinterpret_cast<const float4*>(Wih0 + i * 4);
        wsh[i*4+0] = wv.x; wsh[i*4+1] = wv.y; wsh[i*4+2] = wv.z; wsh[i*4+3] = wv.w;
    }
    // gather embeddings: 256 rows x 8 feats x 2 half-float4s = 4096 float4 loads
    #pragma unroll
    for (int it = 0; it < 16; ++it) {
        int q = tid + it * 256;              // 0..4095
        int p = q >> 1, half = q & 1;
        int r = p >> 3, f = p & 7;           // r: 0..255 global row in block
        int idx = (int)xg[r * 9 + f];
        const float* er = emb + (size_t)idx * 8 + half * 4;
        float4 e = *reinterpret_cast<const float4*>(er);
        float* d = &smem[(r >> 7) * BOFF + (r & 127) * RSTRIDE + f * 8 + half * 4];
        d[0] = e.x; d[1] = e.y; d[2] = e.z; d[3] = e.w;
    }
    smem[(tid >> 7) * BOFF + (tid & 127) * RSTRIDE + 64] = xg[tid * 9 + 8];
    __syncthreads();

    // phase 1: wave w -> batch (w>>1), rows [(w&1)*64, +64)
    {
        float wreg[IN0_];
        #pragma unroll
        for (int k = 0; k < IN0_; ++k) wreg[k] = wsh[g * IN0_ + k];
        const float bias0 = bih0[g] + bhh0[g];
        float* base = smem + (wave >> 1) * BOFF;
        for (int r = 0; r < 64; ++r) {
            const int row = (wave & 1) * 64 + r;
            const float* ir = &base[row * RSTRIDE];
            float a0 = bias0, a1 = 0.0f, a2 = 0.0f, a3 = 0.0f;
            #pragma unroll
            for (int k4 = 0; k4 < 16; ++k4) {
                f32x4 v = *reinterpret_cast<const f32x4*>(ir + k4 * 4);
                float p0 = v.x * wreg[k4*4+0] + v.y * wreg[k4*4+1]
                         + v.z * wreg[k4*4+2] + v.w * wreg[k4*4+3];
                if ((k4 & 3) == 0) a0 += p0;
                else if ((k4 & 3) == 1) a1 += p0;
                else if ((k4 & 3) == 2) a2 += p0;
                else a3 += p0;
            }
            float acc = (a0 + a1) + (a2 + a3) + ir[64] * wreg[64];
            base[row * RSTRIDE + g] = acc;
        }
    }
    __syncthreads();

    if (tid >= 64) return;   // phase 2: wave 0, both batches

    const int j = g & 15;
    float w0[HH], wi1[HH], w1[HH];
    #pragma unroll
    for (int k = 0; k < HH; ++k) {
        w0[k]  = Whh0[g * HH + k];
        wi1[k] = Wih1[g * HH + k];
        w1[k]  = Whh1[g * HH + k];
    }
    const float bias1 = bih1[g] + bhh1[g];
    const int bA = b0, bB = b0 + 1;

    float h0A = h0in[bA * HH + j],            h0B = h0in[bB * HH + j];
    float h1A = h0in[BB * HH + bA * HH + j],  h1B = h0in[BB * HH + bB * HH + j];
    float c0A = c0in[bA * HH + j],            c0B = c0in[bB * HH + j];
    float c1A = c0in[BB * HH + bA * HH + j],  c1B = c0in[BB * HH + bB * HH + j];

    const float* xpA = smem;          // batch A xp rows (stride RSTRIDE)
    const float* xpB = smem + BOFF;   // batch B

    // prologue: layer0 step 0, both batches
    {
        float aA = xpA[g], abA = 0.0f, aB = xpB[g], abB = 0.0f;
        #pragma unroll
        for (int k = 0; k < 8; ++k) {
            float wA = w0[k], wB = w0[k + 8];
            aA  += bcast(h0A, k)     * wA;
            abA += bcast(h0A, k + 8) * wB;
            aB  += bcast(h0B, k)     * wA;
            abB += bcast(h0B, k + 8) * wB;
        }
        float accA = aA + abA, accB = aB + abB;
        float ivA = __shfl(accA, j), fvA = __shfl(accA, j + 16);
        float gvA = __shfl(accA, j + 32), ovA = __shfl(accA, j + 48);
        float ivB = __shfl(accB, j), fvB = __shfl(accB, j + 16);
        float gvB = __shfl(accB, j + 32), ovB = __shfl(accB, j + 48);
        c0A = sigf(fvA) * c0A + sigf(ivA) * tanhfast(gvA);
        c0B = sigf(fvB) * c0B + sigf(ivB) * tanhfast(gvB);
        h0A = sigf(ovA) * tanhfast(c0A);
        h0B = sigf(ovB) * tanhfast(c0B);
    }

    for (int t = 0; t < TT - 1; ++t) {
        float xpnA = xpA[(t + 1) * RSTRIDE + g];
        float xpnB = xpB[(t + 1) * RSTRIDE + g];
        float a1aA = bias1, a1bA = 0.0f, a1cA = 0.0f, a1dA = 0.0f;
        float a0aA = 0.0f,  a0bA = 0.0f;
        float a1aB = bias1, a1bB = 0.0f, a1cB = 0.0f, a1dB = 0.0f;
        float a0aB = 0.0f,  a0bB = 0.0f;
        #pragma unroll
        for (int k = 0; k < 8; ++k) {
            float h0kA  = bcast(h0A, k),     h0k8A = bcast(h0A, k + 8);
            float h1kA  = bcast(h1A, k),     h1k8A = bcast(h1A, k + 8);
            float h0kB  = bcast(h0B, k),     h0k8B = bcast(h0B, k + 8);
            float h1kB  = bcast(h1B, k),     h1k8B = bcast(h1B, k + 8);
            float wiA = wi1[k], wiB = wi1[k + 8];
            float whA = w1[k],  whB = w1[k + 8];
            float w0a = w0[k],  w0b = w0[k + 8];
            a1aA += h0kA  * wiA;  a1bA += h0k8A * wiB;
            a1cA += h1kA  * whA;  a1dA += h1k8A * whB;
            a0aA += h0kA  * w0a;  a0bA += h0k8A * w0b;
            a1aB += h0kB  * wiA;  a1bB += h0k8B * wiB;
            a1cB += h1kB  * whA;  a1dB += h1k8B * whB;
            a0aB += h0kB  * w0a;  a0bB += h0k8B * w0b;
        }
        float acc1A = (a1aA + a1bA) + (a1cA + a1dA);
        float acc0A = xpnA + a0aA + a0bA;
        float acc1B = (a1aB + a1bB) + (a1cB + a1dB);
        float acc0B = xpnB + a0aB + a0bB;
        float iv1A = __shfl(acc1A, j), fv1A = __shfl(acc1A, j + 16);
        float gv1A = __shfl(acc1A, j + 32), ov1A = __shfl(acc1A, j + 48);
        float iv0A = __shfl(acc0A, j), fv0A = __shfl(acc0A, j + 16);
        float gv0A = __shfl(acc0A, j + 32), ov0A = __shfl(acc0A, j + 48);
        float iv1B = __shfl(acc1B, j), fv1B = __shfl(acc1B, j + 16);
        float gv1B = __shfl(acc1B, j + 32), ov1B = __shfl(acc1B, j + 48);
        float iv0B = __shfl(acc0B, j), fv0B = __shfl(acc0B, j + 16);
        float gv0B = __shfl(acc0B, j + 32), ov0B = __shfl(acc0B, j + 48);
        c1A = sigf(fv1A) * c1A + sigf(iv1A) * tanhfast(gv1A);
        c1B = sigf(fv1B) * c1B + sigf(iv1B) * tanhfast(gv1B);
        h1A = sigf(ov1A) * tanhfast(c1A);
        h1B = sigf(ov1B) * tanhfast(c1B);
        c0A = sigf(fv0A) * c0A + sigf(iv0A) * tanhfast(gv0A);
        c0B = sigf(fv0B) * c0B + sigf(iv0B) * tanhfast(gv0B);
        h0A = sigf(ov0A) * tanhfast(c0A);
        h0B = sigf(ov0B) * tanhfast(c0B);
        if (g < HH) {
            y1[(size_t)(bA * TT + t) * HH + g] = h1A;
            y1[(size_t)(bB * TT + t) * HH + g] = h1B;
        }
    }

    // epilogue: layer1 step TT-1, both batches
    {
        float a1aA = bias1, a1bA = 0.0f, a1cA = 0.0f, a1dA = 0.0f;
        float a1aB = bias1, a1bB = 0.0f, a1cB = 0.0f, a1dB = 0.0f;
        #pragma unroll
        for (int k = 0; k < 8; ++k) {
            float wiA = wi1[k], wiB = wi1[k + 8];
            float whA = w1[k],  whB = w1[k + 8];
            a1aA += bcast(h0A, k)     * wiA;  a1bA += bcast(h0A, k + 8) * wiB;
            a1cA += bcast(h1A, k)     * whA;  a1dA += bcast(h1A, k + 8) * whB;
            a1aB += bcast(h0B, k)     * wiA;  a1bB += bcast(h0B, k + 8) * wiB;
            a1cB += bcast(h1B, k)     * whA;  a1dB += bcast(h1B, k + 8) * whB;
        }
        float acc1A = (a1aA + a1bA) + (a1cA + a1dA);
        float acc1B = (a1aB + a1bB) + (a1cB + a1dB);
        float iv1A = __shfl(acc1A, j), fv1A = __shfl(acc1A, j + 16);
        float gv1A = __shfl(acc1A, j + 32), ov1A = __shfl(acc1A, j + 48);
        float iv1B = __shfl(acc1B, j), fv1B = __shfl(acc1B, j + 16);
        float gv1B = __shfl(acc1B, j + 32), ov1B = __shfl(acc1B, j + 48);
        c1A = sigf(fv1A) * c1A + sigf(iv1A) * tanhfast(gv1A);
        c1B = sigf(fv1B) * c1B + sigf(iv1B) * tanhfast(gv1B);
        h1A = sigf(ov1A) * tanhfast(c1A);
        h1B = sigf(ov1B) * tanhfast(c1B);
        if (g < HH) {
            y1[(size_t)(bA * TT + TT - 1) * HH + g] = h1A;
            y1[(size_t)(bB * TT + TT - 1) * HH + g] = h1B;
        }
    }

    if (g < HH) {
        outTail[bA * HH + g]               = h0A;
        outTail[bB * HH + g]               = h0B;
        outTail[BB * HH + bA * HH + g]     = h1A;
        outTail[BB * HH + bB * HH + g]     = h1B;
        outTail[2 * BB * HH + bA * HH + g] = c0A;
        outTail[2 * BB * HH + bB * HH + g] = c0B;
        outTail[3 * BB * HH + bA * HH + g] = c1A;
        outTail[3 * BB * HH + bB * HH + g] = c1B;
    }
}

// ---------------- Kernel B: FC head — byte-identical to round 7 --------------------
__global__ __launch_bounds__(256) void fc_kernel(const float* __restrict__ y1,
                          const float* __restrict__ fcw, const float* __restrict__ fcb,
                          float* __restrict__ out) {
    const int tid  = threadIdx.x;
    const int v0   = blockIdx.x * 1024 + tid * 4;   // column slice (fast grid dim)
    const int row0 = blockIdx.y * 32;               // row band

    if (v0 >= VV) return;

    float w[4][HH];
    #pragma unroll
    for (int jj = 0; jj < 4; ++jj) {
        const float4* wp = reinterpret_cast<const float4*>(fcw + (size_t)(v0 + jj) * HH);
        float4 a = wp[0], b = wp[1], c = wp[2], d = wp[3];
        w[jj][0]=a.x; w[jj][1]=a.y; w[jj][2]=a.z; w[jj][3]=a.w;
        w[jj][4]=b.x; w[jj][5]=b.y; w[jj][6]=b.z; w[jj][7]=b.w;
        w[jj][8]=c.x; w[jj][9]=c.y; w[jj][10]=c.z; w[jj][11]=c.w;
        w[jj][12]=d.x; w[jj][13]=d.y; w[jj][14]=d.z; w[jj][15]=d.w;
    }
    const float4 bias = *reinterpret_cast<const float4*>(fcb + v0);

    const f32x4* yrow = reinterpret_cast<const f32x4*>(y1 + (size_t)row0 * HH);

    float* orow = out + (size_t)row0 * VV + v0;
    #pragma unroll 4
    for (int r = 0; r < 32; ++r) {
        f32x4 y0 = yrow[r * 4 + 0];
        f32x4 y1v = yrow[r * 4 + 1];
        f32x4 y2 = yrow[r * 4 + 2];
        f32x4 y3 = yrow[r * 4 + 3];
        float a0 = bias.x, a1 = bias.y, a2 = bias.z, a3 = bias.w;
        #pragma unroll
        for (int jj = 0; jj < 4; ++jj) {
            float* wj = w[jj];
            float acc = y0.x*wj[0] + y0.y*wj[1] + y0.z*wj[2] + y0.w*wj[3]
                      + y1v.x*wj[4] + y1v.y*wj[5] + y1v.z*wj[6] + y1v.w*wj[7]
                      + y2.x*wj[8] + y2.y*wj[9] + y2.z*wj[10] + y2.w*wj[11]
                      + y3.x*wj[12] + y3.y*wj[13] + y3.z*wj[14] + y3.w*wj[15];
            if (jj == 0) a0 += acc;
            else if (jj == 1) a1 += acc;
            else if (jj == 2) a2 += acc;
            else a3 += acc;
        }
        f32x4 o;
        o.x = a0; o.y = a1; o.z = a2; o.w = a3;
        __builtin_nontemporal_store(o, reinterpret_cast<f32x4*>(orow));
        orow += VV;
    }
}

extern "C" void kernel_launch(void* const* d_in, const int* in_sizes, int n_in,
                              void* d_out, int out_size, void* d_ws, size_t ws_size,
                              hipStream_t stream) {
    const float* x    = (const float*)d_in[0];
    const float* h0   = (const float*)d_in[1];
    const float* c0   = (const float*)d_in[2];
    const float* emb  = (const float*)d_in[3];
    const float* Wih0 = (const float*)d_in[4];
    const float* Whh0 = (const float*)d_in[5];
    const float* bih0 = (const float*)d_in[6];
    const float* bhh0 = (const float*)d_in[7];
    const float* Wih1 = (const float*)d_in[8];
    const float* Whh1 = (const float*)d_in[9];
    const float* bih1 = (const float*)d_in[10];
    const float* bhh1 = (const float*)d_in[11];
    const float* fcw  = (const float*)d_in[12];
    const float* fcb  = (const float*)d_in[13];

    float* out = (float*)d_out;
    float* y1  = (float*)d_ws;                     // NROWS*16 floats
    float* outTail = out + (size_t)NROWS * VV;     // hN then cN

    const size_t lds_bytes = (2 * BOFF + GG * IN0_) * sizeof(float);  // 86272
    fused_front<<<BB / 2, 256, lds_bytes, stream>>>(x, emb, Wih0, bih0, bhh0, h0, c0,
                                        Whh0, Wih1, Whh1, bih1, bhh1, y1, outTail);
    fc_kernel<<<dim3(32, NROWS / 32), 256, 0, stream>>>(y1, fcw, fcb, out);
}

// Round 14
// 269.638 us; speedup vs baseline: 1.2849x; 1.2849x over previous
//
#include <hip/hip_runtime.h>
#include <math.h>

#define BB 64
#define TT 128
#define HH 16
#define GG 64      // 4*H
#define IN0_ 65
#define VV 32000
#define NROWS (BB*TT)   // 8192
#define RSTRIDE 68      // insh row stride (floats), 16B-aligned

typedef float f32x4 __attribute__((ext_vector_type(4)));

__device__ __forceinline__ float sigf(float x) {
    return 1.0f / (1.0f + __expf(-x));
}
__device__ __forceinline__ float tanhfast(float x) {
    return 1.0f - 2.0f / (__expf(2.0f * x) + 1.0f);
}
__device__ __forceinline__ float bcast(float v, int lane) {
    return __uint_as_float(__builtin_amdgcn_readlane(__float_as_uint(v), lane));
}

// ---------------- Kernel A: fused front, 2-wave pipelined recurrence ---------------
// 64 blocks x 128 threads (2 waves). Phase 1: both waves compute xp (64 rows each).
// Phase 2: wave0 = layer0 chain + z1 partial (h0-part of layer1 preact) -> LDS;
//          wave1 = layer1 chain consuming z1. One __syncthreads per step (legal,
//          outside wave-conditionals); waves pipeline with skew 1 on separate SIMDs.
__global__ __launch_bounds__(128) void fused_front(const float* __restrict__ x,
                           const float* __restrict__ emb,
                           const float* __restrict__ Wih0, const float* __restrict__ bih0,
                           const float* __restrict__ bhh0,
                           const float* __restrict__ h0in, const float* __restrict__ c0in,
                           const float* __restrict__ Whh0,
                           const float* __restrict__ Wih1, const float* __restrict__ Whh1,
                           const float* __restrict__ bih1, const float* __restrict__ bhh1,
                           float* __restrict__ y1, float* __restrict__ outTail) {
    __shared__ float insh[TT * RSTRIDE];   // 34816 B: inp rows -> xp rows (in-place)
    __shared__ float wsh[GG * IN0_];       // 16640 B: Wih0 staged
    __shared__ float z1buf[2][GG];         // 512 B: per-step layer1 h0-partials
    const int b   = blockIdx.x;
    const int tid = threadIdx.x;           // 0..127
    const int wave = tid >> 6, g = tid & 63;
    const float* xb = x + (size_t)b * TT * 9;

    // stage Wih0 (coalesced float4)
    for (int i = tid; i < GG * IN0_ / 4; i += 128) {
        float4 wv = *reinterpret_cast<const float4*>(Wih0 + i * 4);
        wsh[i*4+0] = wv.x; wsh[i*4+1] = wv.y; wsh[i*4+2] = wv.z; wsh[i*4+3] = wv.w;
    }
    // gather embeddings: 128 rows x 8 feats x 2 half-float4s = 2048 float4 loads
    #pragma unroll
    for (int it = 0; it < 16; ++it) {
        int q = tid + it * 128;            // 0..2047
        int p = q >> 1, half = q & 1;
        int r = p >> 3, f = p & 7;
        int idx = (int)xb[r * 9 + f];
        const float* er = emb + (size_t)idx * 8 + half * 4;
        float4 e = *reinterpret_cast<const float4*>(er);
        float* d = &insh[r * RSTRIDE + f * 8 + half * 4];
        d[0] = e.x; d[1] = e.y; d[2] = e.z; d[3] = e.w;
    }
    insh[tid * RSTRIDE + 64] = xb[tid * 9 + 8];
    __syncthreads();

    // phase 1: wave w -> rows [w*64, w*64+64)
    {
        float wreg[IN0_];
        #pragma unroll
        for (int k = 0; k < IN0_; ++k) wreg[k] = wsh[g * IN0_ + k];
        const float bias0 = bih0[g] + bhh0[g];
        for (int r = 0; r < 64; ++r) {
            const int row = wave * 64 + r;
            const float* ir = &insh[row * RSTRIDE];
            float a0 = bias0, a1 = 0.0f, a2 = 0.0f, a3 = 0.0f;
            #pragma unroll
            for (int k4 = 0; k4 < 16; ++k4) {
                f32x4 v = *reinterpret_cast<const f32x4*>(ir + k4 * 4);
                float p0 = v.x * wreg[k4*4+0] + v.y * wreg[k4*4+1]
                         + v.z * wreg[k4*4+2] + v.w * wreg[k4*4+3];
                if ((k4 & 3) == 0) a0 += p0;
                else if ((k4 & 3) == 1) a1 += p0;
                else if ((k4 & 3) == 2) a2 += p0;
                else a3 += p0;
            }
            float acc = (a0 + a1) + (a2 + a3) + ir[64] * wreg[64];
            insh[row * RSTRIDE + g] = acc;
        }
    }
    __syncthreads();

    const int j = g & 15;
    // per-wave weight registers
    float wa[HH], wb[HH];   // wave0: wa=Whh0 row, wb=Wih1 row; wave1: wa=Whh1 row
    #pragma unroll
    for (int k = 0; k < HH; ++k) {
        wa[k] = (wave == 0) ? Whh0[g * HH + k] : Whh1[g * HH + k];
        wb[k] = (wave == 0) ? Wih1[g * HH + k] : 0.0f;
    }
    const float bias1 = bih1[g] + bhh1[g];

    // state: wave0 holds (h0,c0); wave1 holds (h1,c1)
    float hv = (wave == 0) ? h0in[b * HH + j] : h0in[BB * HH + b * HH + j];
    float cv = (wave == 0) ? c0in[b * HH + j] : c0in[BB * HH + b * HH + j];

    for (int t = 0; t < TT; ++t) {
        if (wave == 0) {
            // layer0 step t
            float aa = insh[t * RSTRIDE + g], ab = 0.0f;
            #pragma unroll
            for (int k = 0; k < 8; ++k) {
                aa += bcast(hv, k) * wa[k];
                ab += bcast(hv, k + 8) * wa[k + 8];
            }
            float acc = aa + ab;
            float iv = __shfl(acc, j), fv = __shfl(acc, j + 16);
            float gv = __shfl(acc, j + 32), ov = __shfl(acc, j + 48);
            cv = sigf(fv) * cv + sigf(iv) * tanhfast(gv);
            hv = sigf(ov) * tanhfast(cv);
            // z1 partial with new h0(t)
            float za = 0.0f, zb = 0.0f;
            #pragma unroll
            for (int k = 0; k < 8; ++k) {
                za += bcast(hv, k) * wb[k];
                zb += bcast(hv, k + 8) * wb[k + 8];
            }
            z1buf[t & 1][g] = za + zb;
        }
        __syncthreads();
        if (wave == 1) {
            // layer1 step t
            float aa = bias1 + z1buf[t & 1][g], ab = 0.0f;
            #pragma unroll
            for (int k = 0; k < 8; ++k) {
                aa += bcast(hv, k) * wa[k];
                ab += bcast(hv, k + 8) * wa[k + 8];
            }
            float acc = aa + ab;
            float iv = __shfl(acc, j), fv = __shfl(acc, j + 16);
            float gv = __shfl(acc, j + 32), ov = __shfl(acc, j + 48);
            cv = sigf(fv) * cv + sigf(iv) * tanhfast(gv);
            hv = sigf(ov) * tanhfast(cv);
            if (g < HH) y1[(size_t)(b * TT + t) * HH + g] = hv;
        }
    }

    if (g < HH) {
        if (wave == 0) {
            outTail[b * HH + g]               = hv;   // h0T
            outTail[2 * BB * HH + b * HH + g] = cv;   // c0T
        } else {
            outTail[BB * HH + b * HH + g]     = hv;   // h1T
            outTail[3 * BB * HH + b * HH + g] = cv;   // c1T
        }
    }
}

// ---------------- Kernel B: FC head — byte-identical to round 7 --------------------
__global__ __launch_bounds__(256) void fc_kernel(const float* __restrict__ y1,
                          const float* __restrict__ fcw, const float* __restrict__ fcb,
                          float* __restrict__ out) {
    const int tid  = threadIdx.x;
    const int v0   = blockIdx.x * 1024 + tid * 4;   // column slice (fast grid dim)
    const int row0 = blockIdx.y * 32;               // row band

    if (v0 >= VV) return;

    float w[4][HH];
    #pragma unroll
    for (int jj = 0; jj < 4; ++jj) {
        const float4* wp = reinterpret_cast<const float4*>(fcw + (size_t)(v0 + jj) * HH);
        float4 a = wp[0], b = wp[1], c = wp[2], d = wp[3];
        w[jj][0]=a.x; w[jj][1]=a.y; w[jj][2]=a.z; w[jj][3]=a.w;
        w[jj][4]=b.x; w[jj][5]=b.y; w[jj][6]=b.z; w[jj][7]=b.w;
        w[jj][8]=c.x; w[jj][9]=c.y; w[jj][10]=c.z; w[jj][11]=c.w;
        w[jj][12]=d.x; w[jj][13]=d.y; w[jj][14]=d.z; w[jj][15]=d.w;
    }
    const float4 bias = *reinterpret_cast<const float4*>(fcb + v0);

    const f32x4* yrow = reinterpret_cast<const f32x4*>(y1 + (size_t)row0 * HH);

    float* orow = out + (size_t)row0 * VV + v0;
    #pragma unroll 4
    for (int r = 0; r < 32; ++r) {
        f32x4 y0 = yrow[r * 4 + 0];
        f32x4 y1v = yrow[r * 4 + 1];
        f32x4 y2 = yrow[r * 4 + 2];
        f32x4 y3 = yrow[r * 4 + 3];
        float a0 = bias.x, a1 = bias.y, a2 = bias.z, a3 = bias.w;
        #pragma unroll
        for (int jj = 0; jj < 4; ++jj) {
            float* wj = w[jj];
            float acc = y0.x*wj[0] + y0.y*wj[1] + y0.z*wj[2] + y0.w*wj[3]
                      + y1v.x*wj[4] + y1v.y*wj[5] + y1v.z*wj[6] + y1v.w*wj[7]
                      + y2.x*wj[8] + y2.y*wj[9] + y2.z*wj[10] + y2.w*wj[11]
                      + y3.x*wj[12] + y3.y*wj[13] + y3.z*wj[14] + y3.w*wj[15];
            if (jj == 0) a0 += acc;
            else if (jj == 1) a1 += acc;
            else if (jj == 2) a2 += acc;
            else a3 += acc;
        }
        f32x4 o;
        o.x = a0; o.y = a1; o.z = a2; o.w = a3;
        __builtin_nontemporal_store(o, reinterpret_cast<f32x4*>(orow));
        orow += VV;
    }
}

extern "C" void kernel_launch(void* const* d_in, const int* in_sizes, int n_in,
                              void* d_out, int out_size, void* d_ws, size_t ws_size,
                              hipStream_t stream) {
    const float* x    = (const float*)d_in[0];
    const float* h0   = (const float*)d_in[1];
    const float* c0   = (const float*)d_in[2];
    const float* emb  = (const float*)d_in[3];
    const float* Wih0 = (const float*)d_in[4];
    const float* Whh0 = (const float*)d_in[5];
    const float* bih0 = (const float*)d_in[6];
    const float* bhh0 = (const float*)d_in[7];
    const float* Wih1 = (const float*)d_in[8];
    const float* Whh1 = (const float*)d_in[9];
    const float* bih1 = (const float*)d_in[10];
    const float* bhh1 = (const float*)d_in[11];
    const float* fcw  = (const float*)d_in[12];
    const float* fcb  = (const float*)d_in[13];

    float* out = (float*)d_out;
    float* y1  = (float*)d_ws;                     // NROWS*16 floats
    float* outTail = out + (size_t)NROWS * VV;     // hN then cN

    fused_front<<<BB, 128, 0, stream>>>(x, emb, Wih0, bih0, bhh0, h0, c0,
                                        Whh0, Wih1, Whh1, bih1, bhh1, y1, outTail);
    fc_kernel<<<dim3(32, NROWS / 32), 256, 0, stream>>>(y1, fcw, fcb, out);
}

// Round 15
// 255.836 us; speedup vs baseline: 1.3543x; 1.0539x over previous
//
#include <hip/hip_runtime.h>
#include <math.h>

#define BB 64
#define TT 128
#define HH 16
#define GG 64      // 4*H
#define IN0_ 65
#define VV 32000
#define NROWS (BB*TT)   // 8192
#define RSTRIDE 68      // insh row stride (floats), 16B-aligned

typedef float f32x4 __attribute__((ext_vector_type(4)));

__device__ __forceinline__ float bcast(float v, int lane) {
    return __uint_as_float(__builtin_amdgcn_readlane(__float_as_uint(v), lane));
}
__device__ __forceinline__ float fastrcp(float x) {
    return __builtin_amdgcn_rcpf(x);
}
// tanh(x) = 1 - 2/(e^(2x)+1), via v_exp + v_rcp (no fp32 div chain)
__device__ __forceinline__ float tanhc(float x) {
    return 1.0f - 2.0f * fastrcp(__expf(2.0f * x) + 1.0f);
}

// ---------------- Kernel A: fused front, 2-wave pipelined recurrence ---------------
// 64 blocks x 128 threads (2 waves). Phase 1: both waves compute xp (64 rows each).
// Phase 2: wave0 = layer0 chain + z1 partial -> LDS; wave1 = layer1 chain.
// Activation scheme: lane g applies ONE unified activation 1 - m*rcp(e^(s*x)+1)
// to its own gate preact (m,s per-lane constants: sig=(1,1), tanh-gate=(2,2)),
// THEN the four activated values are gathered by shuffle. This replaces
// 10 trans + 5 fp32-div chains per wave-step with 2 exp + 2 rcp on the path.
__global__ __launch_bounds__(128) void fused_front(const float* __restrict__ x,
                           const float* __restrict__ emb,
                           const float* __restrict__ Wih0, const float* __restrict__ bih0,
                           const float* __restrict__ bhh0,
                           const float* __restrict__ h0in, const float* __restrict__ c0in,
                           const float* __restrict__ Whh0,
                           const float* __restrict__ Wih1, const float* __restrict__ Whh1,
                           const float* __restrict__ bih1, const float* __restrict__ bhh1,
                           float* __restrict__ y1, float* __restrict__ outTail) {
    __shared__ float insh[TT * RSTRIDE];   // 34816 B: inp rows -> xp rows (in-place)
    __shared__ float wsh[GG * IN0_];       // 16640 B: Wih0 staged
    __shared__ float z1buf[2][GG];         // 512 B: per-step layer1 h0-partials
    const int b   = blockIdx.x;
    const int tid = threadIdx.x;           // 0..127
    const int wave = tid >> 6, g = tid & 63;
    const float* xb = x + (size_t)b * TT * 9;

    // stage Wih0 (coalesced float4)
    for (int i = tid; i < GG * IN0_ / 4; i += 128) {
        float4 wv = *reinterpret_cast<const float4*>(Wih0 + i * 4);
        wsh[i*4+0] = wv.x; wsh[i*4+1] = wv.y; wsh[i*4+2] = wv.z; wsh[i*4+3] = wv.w;
    }
    // gather embeddings: 128 rows x 8 feats x 2 half-float4s = 2048 float4 loads
    #pragma unroll
    for (int it = 0; it < 16; ++it) {
        int q = tid + it * 128;            // 0..2047
        int p = q >> 1, half = q & 1;
        int r = p >> 3, f = p & 7;
        int idx = (int)xb[r * 9 + f];
        const float* er = emb + (size_t)idx * 8 + half * 4;
        float4 e = *reinterpret_cast<const float4*>(er);
        float* d = &insh[r * RSTRIDE + f * 8 + half * 4];
        d[0] = e.x; d[1] = e.y; d[2] = e.z; d[3] = e.w;
    }
    insh[tid * RSTRIDE + 64] = xb[tid * 9 + 8];
    __syncthreads();

    // phase 1: wave w -> rows [w*64, w*64+64)
    {
        float wreg[IN0_];
        #pragma unroll
        for (int k = 0; k < IN0_; ++k) wreg[k] = wsh[g * IN0_ + k];
        const float bias0 = bih0[g] + bhh0[g];
        for (int r = 0; r < 64; ++r) {
            const int row = wave * 64 + r;
            const float* ir = &insh[row * RSTRIDE];
            float a0 = bias0, a1 = 0.0f, a2 = 0.0f, a3 = 0.0f;
            #pragma unroll
            for (int k4 = 0; k4 < 16; ++k4) {
                f32x4 v = *reinterpret_cast<const f32x4*>(ir + k4 * 4);
                float p0 = v.x * wreg[k4*4+0] + v.y * wreg[k4*4+1]
                         + v.z * wreg[k4*4+2] + v.w * wreg[k4*4+3];
                if ((k4 & 3) == 0) a0 += p0;
                else if ((k4 & 3) == 1) a1 += p0;
                else if ((k4 & 3) == 2) a2 += p0;
                else a3 += p0;
            }
            float acc = (a0 + a1) + (a2 + a3) + ir[64] * wreg[64];
            insh[row * RSTRIDE + g] = acc;
        }
    }
    __syncthreads();

    const int j = g & 15;
    const int type = g >> 4;                       // 0=i, 1=f, 2=g(tanh), 3=o
    const float mconst = (type == 2) ? 2.0f : 1.0f;
    const float sconst = (type == 2) ? 2.0f : 1.0f;

    // per-wave weight registers
    float wa[HH], wb[HH];   // wave0: wa=Whh0 row, wb=Wih1 row; wave1: wa=Whh1 row
    #pragma unroll
    for (int k = 0; k < HH; ++k) {
        wa[k] = (wave == 0) ? Whh0[g * HH + k] : Whh1[g * HH + k];
        wb[k] = (wave == 0) ? Wih1[g * HH + k] : 0.0f;
    }
    const float bias1 = bih1[g] + bhh1[g];

    // state: wave0 holds (h0,c0); wave1 holds (h1,c1)
    float hv = (wave == 0) ? h0in[b * HH + j] : h0in[BB * HH + b * HH + j];
    float cv = (wave == 0) ? c0in[b * HH + j] : c0in[BB * HH + b * HH + j];

    float xpc = insh[g];   // wave0's xp(0); harmless dummy on wave1

    for (int t = 0; t < TT; ++t) {
        if (wave == 0) {
            // prefetch next xp (clamped index; last-iter value unused)
            float xpn = insh[((t + 1) & (TT - 1)) * RSTRIDE + g];
            // layer0 step t: preact for gate g
            float a0 = xpc, a1 = 0.0f, a2 = 0.0f, a3 = 0.0f;
            #pragma unroll
            for (int k = 0; k < 4; ++k) {
                a0 += bcast(hv, k)      * wa[k];
                a1 += bcast(hv, k + 4)  * wa[k + 4];
                a2 += bcast(hv, k + 8)  * wa[k + 8];
                a3 += bcast(hv, k + 12) * wa[k + 12];
            }
            float acc = (a0 + a1) + (a2 + a3);
            // unified activation on own gate, then gather
            float tv = 1.0f - mconst * fastrcp(__expf(sconst * acc) + 1.0f);
            float ti = __shfl(tv, j);
            float tf = __shfl(tv, j + 16);
            float tg = __shfl(tv, j + 32);
            float to = __shfl(tv, j + 48);
            cv = tf * cv + ti * tg;
            hv = to * tanhc(cv);
            // z1 partial with new h0(t)
            float za = 0.0f, zb = 0.0f;
            #pragma unroll
            for (int k = 0; k < 8; ++k) {
                za += bcast(hv, k)     * wb[k];
                zb += bcast(hv, k + 8) * wb[k + 8];
            }
            z1buf[t & 1][g] = za + zb;
            xpc = xpn;
        }
        __syncthreads();
        if (wave == 1) {
            // layer1 step t
            float a0 = bias1 + z1buf[t & 1][g], a1 = 0.0f, a2 = 0.0f, a3 = 0.0f;
            #pragma unroll
            for (int k = 0; k < 4; ++k) {
                a0 += bcast(hv, k)      * wa[k];
                a1 += bcast(hv, k + 4)  * wa[k + 4];
                a2 += bcast(hv, k + 8)  * wa[k + 8];
                a3 += bcast(hv, k + 12) * wa[k + 12];
            }
            float acc = (a0 + a1) + (a2 + a3);
            float tv = 1.0f - mconst * fastrcp(__expf(sconst * acc) + 1.0f);
            float ti = __shfl(tv, j);
            float tf = __shfl(tv, j + 16);
            float tg = __shfl(tv, j + 32);
            float to = __shfl(tv, j + 48);
            cv = tf * cv + ti * tg;
            hv = to * tanhc(cv);
            if (g < HH) y1[(size_t)(b * TT + t) * HH + g] = hv;
        }
    }

    if (g < HH) {
        if (wave == 0) {
            outTail[b * HH + g]               = hv;   // h0T
            outTail[2 * BB * HH + b * HH + g] = cv;   // c0T
        } else {
            outTail[BB * HH + b * HH + g]     = hv;   // h1T
            outTail[3 * BB * HH + b * HH + g] = cv;   // c1T
        }
    }
}

// ---------------- Kernel B: FC head — byte-identical to round 7 --------------------
__global__ __launch_bounds__(256) void fc_kernel(const float* __restrict__ y1,
                          const float* __restrict__ fcw, const float* __restrict__ fcb,
                          float* __restrict__ out) {
    const int tid  = threadIdx.x;
    const int v0   = blockIdx.x * 1024 + tid * 4;   // column slice (fast grid dim)
    const int row0 = blockIdx.y * 32;               // row band

    if (v0 >= VV) return;

    float w[4][HH];
    #pragma unroll
    for (int jj = 0; jj < 4; ++jj) {
        const float4* wp = reinterpret_cast<const float4*>(fcw + (size_t)(v0 + jj) * HH);
        float4 a = wp[0], b = wp[1], c = wp[2], d = wp[3];
        w[jj][0]=a.x; w[jj][1]=a.y; w[jj][2]=a.z; w[jj][3]=a.w;
        w[jj][4]=b.x; w[jj][5]=b.y; w[jj][6]=b.z; w[jj][7]=b.w;
        w[jj][8]=c.x; w[jj][9]=c.y; w[jj][10]=c.z; w[jj][11]=c.w;
        w[jj][12]=d.x; w[jj][13]=d.y; w[jj][14]=d.z; w[jj][15]=d.w;
    }
    const float4 bias = *reinterpret_cast<const float4*>(fcb + v0);

    const f32x4* yrow = reinterpret_cast<const f32x4*>(y1 + (size_t)row0 * HH);

    float* orow = out + (size_t)row0 * VV + v0;
    #pragma unroll 4
    for (int r = 0; r < 32; ++r) {
        f32x4 y0 = yrow[r * 4 + 0];
        f32x4 y1v = yrow[r * 4 + 1];
        f32x4 y2 = yrow[r * 4 + 2];
        f32x4 y3 = yrow[r * 4 + 3];
        float a0 = bias.x, a1 = bias.y, a2 = bias.z, a3 = bias.w;
        #pragma unroll
        for (int jj = 0; jj < 4; ++jj) {
            float* wj = w[jj];
            float acc = y0.x*wj[0] + y0.y*wj[1] + y0.z*wj[2] + y0.w*wj[3]
                      + y1v.x*wj[4] + y1v.y*wj[5] + y1v.z*wj[6] + y1v.w*wj[7]
                      + y2.x*wj[8] + y2.y*wj[9] + y2.z*wj[10] + y2.w*wj[11]
                      + y3.x*wj[12] + y3.y*wj[13] + y3.z*wj[14] + y3.w*wj[15];
            if (jj == 0) a0 += acc;
            else if (jj == 1) a1 += acc;
            else if (jj == 2) a2 += acc;
            else a3 += acc;
        }
        f32x4 o;
        o.x = a0; o.y = a1; o.z = a2; o.w = a3;
        __builtin_nontemporal_store(o, reinterpret_cast<f32x4*>(orow));
        orow += VV;
    }
}

extern "C" void kernel_launch(void* const* d_in, const int* in_sizes, int n_in,
                              void* d_out, int out_size, void* d_ws, size_t ws_size,
                              hipStream_t stream) {
    const float* x    = (const float*)d_in[0];
    const float* h0   = (const float*)d_in[1];
    const float* c0   = (const float*)d_in[2];
    const float* emb  = (const float*)d_in[3];
    const float* Wih0 = (const float*)d_in[4];
    const float* Whh0 = (const float*)d_in[5];
    const float* bih0 = (const float*)d_in[6];
    const float* bhh0 = (const float*)d_in[7];
    const float* Wih1 = (const float*)d_in[8];
    const float* Whh1 = (const float*)d_in[9];
    const float* bih1 = (const float*)d_in[10];
    const float* bhh1 = (const float*)d_in[11];
    const float* fcw  = (const float*)d_in[12];
    const float* fcb  = (const float*)d_in[13];

    float* out = (float*)d_out;
    float* y1  = (float*)d_ws;                     // NROWS*16 floats
    float* outTail = out + (size_t)NROWS * VV;     // hN then cN

    fused_front<<<BB, 128, 0, stream>>>(x, emb, Wih0, bih0, bhh0, h0, c0,
                                        Whh0, Wih1, Whh1, bih1, bhh1, y1, outTail);
    fc_kernel<<<dim3(32, NROWS / 32), 256, 0, stream>>>(y1, fcw, fcb, out);
}

// Round 16
// 255.466 us; speedup vs baseline: 1.3562x; 1.0014x over previous
//
#include <hip/hip_runtime.h>
#include <math.h>

#define BB 64
#define TT 128
#define HH 16
#define GG 64      // 4*H
#define IN0_ 65
#define VV 32000
#define NROWS (BB*TT)   // 8192
#define RSTRIDE 68      // insh row stride (floats), 16B-aligned

typedef float f32x4 __attribute__((ext_vector_type(4)));

__device__ __forceinline__ float bcast(float v, int lane) {
    return __uint_as_float(__builtin_amdgcn_readlane(__float_as_uint(v), lane));
}
__device__ __forceinline__ float fastrcp(float x) {
    return __builtin_amdgcn_rcpf(x);
}
// tanh(x) = 1 - 2/(e^(2x)+1), via v_exp + v_rcp (no fp32 div chain)
__device__ __forceinline__ float tanhc(float x) {
    return 1.0f - 2.0f * fastrcp(__expf(2.0f * x) + 1.0f);
}

// ---------------- Kernel A: fused front ------------------------------------------
// 64 blocks x 256 threads (4 waves). Phase 1: ALL 4 waves compute xp (32 rows each
// — restores R7's phase-1 parallelism). Phase 2: waves 0/1 run the proven 2-wave
// pipelined recurrence (wave0=layer0+z1, wave1=layer1); waves 2/3 traverse the same
// loop executing only the block-uniform barrier each step (cheap; separate SIMDs).
__global__ __launch_bounds__(256) void fused_front(const float* __restrict__ x,
                           const float* __restrict__ emb,
                           const float* __restrict__ Wih0, const float* __restrict__ bih0,
                           const float* __restrict__ bhh0,
                           const float* __restrict__ h0in, const float* __restrict__ c0in,
                           const float* __restrict__ Whh0,
                           const float* __restrict__ Wih1, const float* __restrict__ Whh1,
                           const float* __restrict__ bih1, const float* __restrict__ bhh1,
                           float* __restrict__ y1, float* __restrict__ outTail) {
    __shared__ float insh[TT * RSTRIDE];   // 34816 B: inp rows -> xp rows (in-place)
    __shared__ float wsh[GG * IN0_];       // 16640 B: Wih0 staged
    __shared__ float z1buf[2][GG];         // 512 B: per-step layer1 h0-partials
    const int b   = blockIdx.x;
    const int tid = threadIdx.x;           // 0..255
    const int wave = tid >> 6, g = tid & 63;
    const float* xb = x + (size_t)b * TT * 9;

    // stage Wih0 (coalesced float4)
    for (int i = tid; i < GG * IN0_ / 4; i += 256) {
        float4 wv = *reinterpret_cast<const float4*>(Wih0 + i * 4);
        wsh[i*4+0] = wv.x; wsh[i*4+1] = wv.y; wsh[i*4+2] = wv.z; wsh[i*4+3] = wv.w;
    }
    // gather embeddings: 128 rows x 8 feats x 2 half-float4s = 2048 float4 loads
    #pragma unroll
    for (int it = 0; it < 8; ++it) {
        int q = tid + it * 256;            // 0..2047
        int p = q >> 1, half = q & 1;
        int r = p >> 3, f = p & 7;
        int idx = (int)xb[r * 9 + f];
        const float* er = emb + (size_t)idx * 8 + half * 4;
        float4 e = *reinterpret_cast<const float4*>(er);
        float* d = &insh[r * RSTRIDE + f * 8 + half * 4];
        d[0] = e.x; d[1] = e.y; d[2] = e.z; d[3] = e.w;
    }
    if (tid < TT) insh[tid * RSTRIDE + 64] = xb[tid * 9 + 8];
    __syncthreads();

    // phase 1: wave w -> rows [w*32, w*32+32)
    {
        float wreg[IN0_];
        #pragma unroll
        for (int k = 0; k < IN0_; ++k) wreg[k] = wsh[g * IN0_ + k];
        const float bias0 = bih0[g] + bhh0[g];
        for (int r = 0; r < 32; ++r) {
            const int row = wave * 32 + r;
            const float* ir = &insh[row * RSTRIDE];
            float a0 = bias0, a1 = 0.0f, a2 = 0.0f, a3 = 0.0f;
            #pragma unroll
            for (int k4 = 0; k4 < 16; ++k4) {
                f32x4 v = *reinterpret_cast<const f32x4*>(ir + k4 * 4);
                float p0 = v.x * wreg[k4*4+0] + v.y * wreg[k4*4+1]
                         + v.z * wreg[k4*4+2] + v.w * wreg[k4*4+3];
                if ((k4 & 3) == 0) a0 += p0;
                else if ((k4 & 3) == 1) a1 += p0;
                else if ((k4 & 3) == 2) a2 += p0;
                else a3 += p0;
            }
            float acc = (a0 + a1) + (a2 + a3) + ir[64] * wreg[64];
            insh[row * RSTRIDE + g] = acc;
        }
    }
    __syncthreads();

    const int j = g & 15;
    const int type = g >> 4;                       // 0=i, 1=f, 2=g(tanh), 3=o
    const float mconst = (type == 2) ? 2.0f : 1.0f;
    const float sconst = (type == 2) ? 2.0f : 1.0f;

    // per-wave weight registers (waves 2/3 load harmlessly, never use)
    float wa[HH], wb[HH];   // wave0: wa=Whh0 row, wb=Wih1 row; wave1: wa=Whh1 row
    #pragma unroll
    for (int k = 0; k < HH; ++k) {
        wa[k] = (wave == 0) ? Whh0[g * HH + k] : Whh1[g * HH + k];
        wb[k] = (wave == 0) ? Wih1[g * HH + k] : 0.0f;
    }
    const float bias1 = bih1[g] + bhh1[g];

    // state: wave0 holds (h0,c0); wave1 holds (h1,c1)
    float hv = (wave == 0) ? h0in[b * HH + j] : h0in[BB * HH + b * HH + j];
    float cv = (wave == 0) ? c0in[b * HH + j] : c0in[BB * HH + b * HH + j];

    float xpc = insh[g];   // wave0's xp(0); harmless dummy on other waves

    for (int t = 0; t < TT; ++t) {
        if (wave == 0) {
            // prefetch next xp (wrapped index; last-iter value unused)
            float xpn = insh[((t + 1) & (TT - 1)) * RSTRIDE + g];
            // layer0 step t: preact for gate g
            float a0 = xpc, a1 = 0.0f, a2 = 0.0f, a3 = 0.0f;
            #pragma unroll
            for (int k = 0; k < 4; ++k) {
                a0 += bcast(hv, k)      * wa[k];
                a1 += bcast(hv, k + 4)  * wa[k + 4];
                a2 += bcast(hv, k + 8)  * wa[k + 8];
                a3 += bcast(hv, k + 12) * wa[k + 12];
            }
            float acc = (a0 + a1) + (a2 + a3);
            // unified activation on own gate, then gather
            float tv = 1.0f - mconst * fastrcp(__expf(sconst * acc) + 1.0f);
            float ti = __shfl(tv, j);
            float tf = __shfl(tv, j + 16);
            float tg = __shfl(tv, j + 32);
            float to = __shfl(tv, j + 48);
            cv = tf * cv + ti * tg;
            hv = to * tanhc(cv);
            // z1 partial with new h0(t)
            float za = 0.0f, zb = 0.0f;
            #pragma unroll
            for (int k = 0; k < 8; ++k) {
                za += bcast(hv, k)     * wb[k];
                zb += bcast(hv, k + 8) * wb[k + 8];
            }
            z1buf[t & 1][g] = za + zb;
            xpc = xpn;
        }
        __syncthreads();
        if (wave == 1) {
            // layer1 step t
            float a0 = bias1 + z1buf[t & 1][g], a1 = 0.0f, a2 = 0.0f, a3 = 0.0f;
            #pragma unroll
            for (int k = 0; k < 4; ++k) {
                a0 += bcast(hv, k)      * wa[k];
                a1 += bcast(hv, k + 4)  * wa[k + 4];
                a2 += bcast(hv, k + 8)  * wa[k + 8];
                a3 += bcast(hv, k + 12) * wa[k + 12];
            }
            float acc = (a0 + a1) + (a2 + a3);
            float tv = 1.0f - mconst * fastrcp(__expf(sconst * acc) + 1.0f);
            float ti = __shfl(tv, j);
            float tf = __shfl(tv, j + 16);
            float tg = __shfl(tv, j + 32);
            float to = __shfl(tv, j + 48);
            cv = tf * cv + ti * tg;
            hv = to * tanhc(cv);
            if (g < HH) y1[(size_t)(b * TT + t) * HH + g] = hv;
        }
    }

    if (g < HH) {
        if (wave == 0) {
            outTail[b * HH + g]               = hv;   // h0T
            outTail[2 * BB * HH + b * HH + g] = cv;   // c0T
        } else if (wave == 1) {
            outTail[BB * HH + b * HH + g]     = hv;   // h1T
            outTail[3 * BB * HH + b * HH + g] = cv;   // c1T
        }
    }
}

// ---------------- Kernel B: FC head — byte-identical to round 7 --------------------
__global__ __launch_bounds__(256) void fc_kernel(const float* __restrict__ y1,
                          const float* __restrict__ fcw, const float* __restrict__ fcb,
                          float* __restrict__ out) {
    const int tid  = threadIdx.x;
    const int v0   = blockIdx.x * 1024 + tid * 4;   // column slice (fast grid dim)
    const int row0 = blockIdx.y * 32;               // row band

    if (v0 >= VV) return;

    float w[4][HH];
    #pragma unroll
    for (int jj = 0; jj < 4; ++jj) {
        const float4* wp = reinterpret_cast<const float4*>(fcw + (size_t)(v0 + jj) * HH);
        float4 a = wp[0], b = wp[1], c = wp[2], d = wp[3];
        w[jj][0]=a.x; w[jj][1]=a.y; w[jj][2]=a.z; w[jj][3]=a.w;
        w[jj][4]=b.x; w[jj][5]=b.y; w[jj][6]=b.z; w[jj][7]=b.w;
        w[jj][8]=c.x; w[jj][9]=c.y; w[jj][10]=c.z; w[jj][11]=c.w;
        w[jj][12]=d.x; w[jj][13]=d.y; w[jj][14]=d.z; w[jj][15]=d.w;
    }
    const float4 bias = *reinterpret_cast<const float4*>(fcb + v0);

    const f32x4* yrow = reinterpret_cast<const f32x4*>(y1 + (size_t)row0 * HH);

    float* orow = out + (size_t)row0 * VV + v0;
    #pragma unroll 4
    for (int r = 0; r < 32; ++r) {
        f32x4 y0 = yrow[r * 4 + 0];
        f32x4 y1v = yrow[r * 4 + 1];
        f32x4 y2 = yrow[r * 4 + 2];
        f32x4 y3 = yrow[r * 4 + 3];
        float a0 = bias.x, a1 = bias.y, a2 = bias.z, a3 = bias.w;
        #pragma unroll
        for (int jj = 0; jj < 4; ++jj) {
            float* wj = w[jj];
            float acc = y0.x*wj[0] + y0.y*wj[1] + y0.z*wj[2] + y0.w*wj[3]
                      + y1v.x*wj[4] + y1v.y*wj[5] + y1v.z*wj[6] + y1v.w*wj[7]
                      + y2.x*wj[8] + y2.y*wj[9] + y2.z*wj[10] + y2.w*wj[11]
                      + y3.x*wj[12] + y3.y*wj[13] + y3.z*wj[14] + y3.w*wj[15];
            if (jj == 0) a0 += acc;
            else if (jj == 1) a1 += acc;
            else if (jj == 2) a2 += acc;
            else a3 += acc;
        }
        f32x4 o;
        o.x = a0; o.y = a1; o.z = a2; o.w = a3;
        __builtin_nontemporal_store(o, reinterpret_cast<f32x4*>(orow));
        orow += VV;
    }
}

extern "C" void kernel_launch(void* const* d_in, const int* in_sizes, int n_in,
                              void* d_out, int out_size, void* d_ws, size_t ws_size,
                              hipStream_t stream) {
    const float* x    = (const float*)d_in[0];
    const float* h0   = (const float*)d_in[1];
    const float* c0   = (const float*)d_in[2];
    const float* emb  = (const float*)d_in[3];
    const float* Wih0 = (const float*)d_in[4];
    const float* Whh0 = (const float*)d_in[5];
    const float* bih0 = (const float*)d_in[6];
    const float* bhh0 = (const float*)d_in[7];
    const float* Wih1 = (const float*)d_in[8];
    const float* Whh1 = (const float*)d_in[9];
    const float* bih1 = (const float*)d_in[10];
    const float* bhh1 = (const float*)d_in[11];
    const float* fcw  = (const float*)d_in[12];
    const float* fcb  = (const float*)d_in[13];

    float* out = (float*)d_out;
    float* y1  = (float*)d_ws;                     // NROWS*16 floats
    float* outTail = out + (size_t)NROWS * VV;     // hN then cN

    fused_front<<<BB, 256, 0, stream>>>(x, emb, Wih0, bih0, bhh0, h0, c0,
                                        Whh0, Wih1, Whh1, bih1, bhh1, y1, outTail);
    fc_kernel<<<dim3(32, NROWS / 32), 256, 0, stream>>>(y1, fcw, fcb, out);
}